// Round 1
// baseline (450.027 us; speedup 1.0000x reference)
//
#include <hip/hip_runtime.h>
#include <stdint.h>

#define Bdim 16
#define Sdim 4096
#define Ddim 512
#define Hdim 512
#define Mdim (Bdim*Sdim)      // 65536
#define N3   (3*Hdim)         // 1536
#define Kdim Ddim             // 512
#define NCHUNK 16
#define CLEN  (Sdim/NCHUNK)   // 256

typedef __bf16 bf16;
typedef __bf16 bf16x4 __attribute__((ext_vector_type(4)));
typedef __bf16 bf16x8 __attribute__((ext_vector_type(8)));
typedef float  f32x4  __attribute__((ext_vector_type(4)));

__device__ inline void gload_lds16(const void* g, void* l) {
  __builtin_amdgcn_global_load_lds(
      (const __attribute__((address_space(1))) uint32_t*)g,
      (__attribute__((address_space(3))) uint32_t*)l, 16, 0, 0);
}

// ---------- fp32 -> bf16 convert (vectorized) ----------
__global__ void __launch_bounds__(256) cvt_kernel(const float4* __restrict__ in,
                                                  bf16x4* __restrict__ out, int n4) {
  int i = blockIdx.x * blockDim.x + threadIdx.x;
  if (i >= n4) return;
  float4 v = in[i];
  bf16x4 o;
  o.x = (bf16)v.x; o.y = (bf16)v.y; o.z = (bf16)v.z; o.w = (bf16)v.w;
  out[i] = o;
}

// ---------- bf16 MFMA GEMM (M=65536,N=1536,K=512), fused activations ----------
// A: (M,K) bf16 row-major; Wb: (N,K) bf16 row-major (B^T layout). C = A*Wb^T.
// Epilogue: col<512 -> tanh -> zbuf ; col<1024 -> sigmoid -> fbuf ; else sigmoid -> ogbuf
#define BM 128
#define BN 128
#define BK 32

__global__ void __launch_bounds__(256) gemm_act_kernel(
    const bf16* __restrict__ A, const bf16* __restrict__ Wb,
    const float* __restrict__ bias,
    float* __restrict__ zbuf, float* __restrict__ fbuf, float* __restrict__ ogbuf) {
  __shared__ bf16 As[BM * BK];  // row-major [128][32]
  __shared__ bf16 Bs[BN * BK];
  const int tid  = threadIdx.x;
  const int wid  = tid >> 6;
  const int lane = tid & 63;
  const int nt = blockIdx.x % (N3 / BN);   // 12 N-tiles (inner -> A reuse in L2)
  const int mt = blockIdx.x / (N3 / BN);
  const int row0 = mt * BM, col0 = nt * BN;
  const int wr = wid >> 1, wc = wid & 1;   // wave quadrant (64x64)

  f32x4 acc[4][4];
  #pragma unroll
  for (int m = 0; m < 4; ++m)
    #pragma unroll
    for (int n = 0; n < 4; ++n)
      acc[m][n] = (f32x4){0.f, 0.f, 0.f, 0.f};

  const bf16* Ag = A  + (size_t)row0 * Kdim;
  const bf16* Bg = Wb + (size_t)col0 * Kdim;

  for (int k0 = 0; k0 < Kdim; k0 += BK) {
    __syncthreads();  // previous iter's LDS reads done
    // stage A,B tiles: 512 chunks of 16B each per tile; wave w covers chunks
    // [w*128 + i*64 + lane]; LDS dest is wave-uniform base + lane*16 (linear).
    #pragma unroll
    for (int i = 0; i < 2; ++i) {
      int c  = wid * 128 + i * 64 + lane;
      int r  = c >> 2, kq = c & 3;
      gload_lds16(Ag + (size_t)r * Kdim + (k0 + kq * 8), &As[(wid * 128 + i * 64) * 8]);
      gload_lds16(Bg + (size_t)r * Kdim + (k0 + kq * 8), &Bs[(wid * 128 + i * 64) * 8]);
    }
    __syncthreads();  // implies vmcnt(0): staged data visible

    bf16x8 af[4], bfr[4];
    #pragma unroll
    for (int m = 0; m < 4; ++m)
      af[m] = *(const bf16x8*)&As[(wr * 64 + m * 16 + (lane & 15)) * BK + (lane >> 4) * 8];
    #pragma unroll
    for (int n = 0; n < 4; ++n)
      bfr[n] = *(const bf16x8*)&Bs[(wc * 64 + n * 16 + (lane & 15)) * BK + (lane >> 4) * 8];
    #pragma unroll
    for (int m = 0; m < 4; ++m)
      #pragma unroll
      for (int n = 0; n < 4; ++n)
        acc[m][n] = __builtin_amdgcn_mfma_f32_16x16x32_bf16(af[m], bfr[n], acc[m][n], 0, 0, 0);
  }

  // epilogue: gate is uniform per block (BN=128 divides each 512-col gate)
  float* dst; int gate;
  if (col0 < Hdim)            { dst = zbuf;  gate = 0; }
  else if (col0 < 2 * Hdim)   { dst = fbuf;  gate = 1; }
  else                        { dst = ogbuf; gate = 2; }
  const int cb = col0 - gate * Hdim;

  #pragma unroll
  for (int n = 0; n < 4; ++n) {
    int col = cb + wc * 64 + n * 16 + (lane & 15);
    float bv = bias[gate * Hdim + col];
    #pragma unroll
    for (int m = 0; m < 4; ++m) {
      #pragma unroll
      for (int r = 0; r < 4; ++r) {
        int grow = row0 + wr * 64 + m * 16 + (lane >> 4) * 4 + r;
        float y = acc[m][n][r] + bv;
        float v;
        if (gate == 0) {                       // tanh(y) = 1 - 2/(e^{2y}+1)
          float e = __expf(2.f * y);
          v = 1.f - 2.f / (e + 1.f);
        } else {                               // sigmoid
          v = 1.f / (1.f + __expf(-y));
        }
        dst[(size_t)grow * Hdim + col] = v;
      }
    }
  }
}

// ---------- scan pass A: per-chunk composite (P = prod(1-f), Q = local scan) ----------
__global__ void __launch_bounds__(256) scanA_kernel(const float* __restrict__ zbuf,
                                                    const float* __restrict__ fbuf,
                                                    float* __restrict__ Pb,
                                                    float* __restrict__ Qb) {
  int u = blockIdx.x * blockDim.x + threadIdx.x;  // 131072 = NCHUNK*B*H
  int h  = u & (Hdim - 1);
  int bc = u >> 9;
  int b  = bc & (Bdim - 1);
  int c  = bc >> 4;
  size_t base = ((size_t)b * Sdim + (size_t)c * CLEN) * Hdim + h;
  float P = 1.f, Q = 0.f;
  #pragma unroll 4
  for (int s = 0; s < CLEN; ++s) {
    float f = fbuf[base], z = zbuf[base];
    float a = 1.f - f;
    Q = a * Q + f * z;
    P = a * P;
    base += Hdim;
  }
  Pb[u] = P; Qb[u] = Q;
}

// ---------- scan pass B: scan chunk composites -> h_in per chunk + c_last ----------
__global__ void __launch_bounds__(256) scanB_kernel(const float* __restrict__ Pb,
                                                    const float* __restrict__ Qb,
                                                    float* __restrict__ hin,
                                                    float* __restrict__ c_last) {
  int t = blockIdx.x * blockDim.x + threadIdx.x;  // 8192 = B*H
  int h = t & (Hdim - 1), b = t >> 9;
  float hs = 0.f;
  #pragma unroll
  for (int c = 0; c < NCHUNK; ++c) {
    hin[c * (Bdim * Hdim) + t] = hs;
    int u = ((c * Bdim + b) << 9) + h;
    hs = Pb[u] * hs + Qb[u];
  }
  c_last[t] = hs;
}

// ---------- scan pass C: rerun chunk with correct h_in, fuse out = og * h ----------
__global__ void __launch_bounds__(256) scanC_kernel(const float* __restrict__ zbuf,
                                                    const float* __restrict__ fbuf,
                                                    const float* __restrict__ hin,
                                                    float* __restrict__ outbuf) {
  int u = blockIdx.x * blockDim.x + threadIdx.x;
  int h  = u & (Hdim - 1);
  int bc = u >> 9;
  int b  = bc & (Bdim - 1);
  int c  = bc >> 4;
  float hs = hin[c * (Bdim * Hdim) + b * Hdim + h];
  size_t base = ((size_t)b * Sdim + (size_t)c * CLEN) * Hdim + h;
  #pragma unroll 4
  for (int s = 0; s < CLEN; ++s) {
    float f = fbuf[base], z = zbuf[base], og = outbuf[base];
    hs = hs + f * (z - hs);        // = f*z + (1-f)*hs
    outbuf[base] = og * hs;
    base += Hdim;
  }
}

extern "C" void kernel_launch(void* const* d_in, const int* in_sizes, int n_in,
                              void* d_out, int out_size, void* d_ws, size_t ws_size,
                              hipStream_t stream) {
  const float* inp  = (const float*)d_in[0];
  const float* W    = (const float*)d_in[1];
  const float* bias = (const float*)d_in[2];
  float* out = (float*)d_out;

  char* ws = (char*)d_ws;
  // workspace layout (bytes)
  bf16*  Abf  = (bf16*)(ws);                        //  67,108,864
  bf16*  Wbf  = (bf16*)(ws + 67108864);             //   1,572,864
  float* zbuf = (float*)(ws + 68681728);            // 134,217,728
  float* fbuf = (float*)(ws + 202899456);           // 134,217,728
  float* Pb   = (float*)(ws + 337117184);           //     524,288
  float* Qb   = (float*)(ws + 337641472);           //     524,288
  float* hin  = (float*)(ws + 338165760);           //     524,288
  // total ~338.7 MB

  // 1) convert inp and W to bf16
  {
    int n4 = (Mdim * Kdim) / 4;  // 8,388,608
    cvt_kernel<<<n4 / 256, 256, 0, stream>>>((const float4*)inp, (bf16x4*)Abf, n4);
  }
  {
    int n4 = (N3 * Kdim) / 4;    // 196,608
    cvt_kernel<<<n4 / 256, 256, 0, stream>>>((const float4*)W, (bf16x4*)Wbf, n4);
  }
  // 2) GEMM + bias + activations; sigmoid(o) goes into d_out (reused in pass C)
  gemm_act_kernel<<<(Mdim / BM) * (N3 / BN), 256, 0, stream>>>(Abf, Wbf, bias,
                                                               zbuf, fbuf, out);
  // 3) chunked linear-recurrence scan
  scanA_kernel<<<(NCHUNK * Bdim * Hdim) / 256, 256, 0, stream>>>(zbuf, fbuf, Pb, Qb);
  scanB_kernel<<<(Bdim * Hdim) / 256, 256, 0, stream>>>(Pb, Qb, hin,
                                                        out + (size_t)Mdim * Hdim);
  scanC_kernel<<<(NCHUNK * Bdim * Hdim) / 256, 256, 0, stream>>>(zbuf, fbuf, hin, out);
}

// Round 2
// 325.657 us; speedup vs baseline: 1.3819x; 1.3819x over previous
//
#include <hip/hip_runtime.h>
#include <stdint.h>

#define Bdim 16
#define Sdim 4096
#define Hdim 512
#define Mdim (Bdim*Sdim)      // 65536
#define N3   (3*Hdim)         // 1536
#define Kdim 512
#define NCHUNK 32
#define CLEN  (Sdim/NCHUNK)   // 128

typedef __bf16 bf16;
typedef __bf16 bf16x4 __attribute__((ext_vector_type(4)));
typedef __bf16 bf16x8 __attribute__((ext_vector_type(8)));
typedef float  f32x4  __attribute__((ext_vector_type(4)));
typedef _Float16 f16;
typedef _Float16 f16x2 __attribute__((ext_vector_type(2)));

__device__ inline void gload_lds16(const void* g, void* l) {
  __builtin_amdgcn_global_load_lds(
      (const __attribute__((address_space(1))) uint32_t*)g,
      (__attribute__((address_space(3))) uint32_t*)l, 16, 0, 0);
}

// ---------- fp32 -> bf16 convert (vectorized) ----------
__global__ void __launch_bounds__(256) cvt_kernel(const float4* __restrict__ in,
                                                  bf16x4* __restrict__ out, int n4) {
  int i = blockIdx.x * blockDim.x + threadIdx.x;
  if (i >= n4) return;
  float4 v = in[i];
  bf16x4 o;
  o.x = (bf16)v.x; o.y = (bf16)v.y; o.z = (bf16)v.z; o.w = (bf16)v.w;
  out[i] = o;
}

// ---------- bf16 MFMA GEMM (M=65536,N=1536,K=512), fused activations ----------
// A: (M,K) bf16 row-major; Wb: (N,K) bf16 row-major. C = A*Wb^T.
// 2-phase double-buffered LDS, XOR-swizzled slots (via pre-swizzled global src).
#define BM 128
#define BN 128
#define BK 32
#define NIT (Kdim/BK)   // 16

__global__ void __launch_bounds__(256) gemm_act_kernel(
    const bf16* __restrict__ A, const bf16* __restrict__ Wb,
    const float* __restrict__ bias,
    f16* __restrict__ zbuf, f16* __restrict__ fbuf, f16* __restrict__ ogbuf) {
  __shared__ bf16 As[2][BM * BK];
  __shared__ bf16 Bs[2][BN * BK];
  const int tid  = threadIdx.x;
  const int wid  = tid >> 6;
  const int lane = tid & 63;
  // XCD-chunked bijective swizzle: 6144 blocks = 8 XCDs x 768
  const int bid = blockIdx.x;
  const int wg  = (bid & 7) * 768 + (bid >> 3);
  const int nt = wg % (N3 / BN);           // 12 N-tiles, inner -> A reuse
  const int mt = wg / (N3 / BN);
  const int row0 = mt * BM, col0 = nt * BN;
  const int wr = wid >> 1, wc = wid & 1;   // wave quadrant (64x64)

  const bf16* Ag = A  + (size_t)row0 * Kdim;
  const bf16* Bg = Wb + (size_t)col0 * Kdim;

  // staging geometry: chunk c covers (row r, k-quad kq); LDS dest linear,
  // global source pre-swizzled: kqs = kq ^ ((r>>1)&3)
  size_t srcOff[2]; int dstOff[2];
  #pragma unroll
  for (int i = 0; i < 2; ++i) {
    int c  = wid * 128 + i * 64 + lane;
    int r  = c >> 2, kq = c & 3;
    int kqs = kq ^ ((r >> 1) & 3);
    srcOff[i] = (size_t)r * Kdim + kqs * 8;
    dstOff[i] = (wid * 128 + i * 64) * 8;  // wave-uniform base (elements)
  }
  // read-side swizzled fragment offsets (elements)
  int aOff[4], bOff[4];
  #pragma unroll
  for (int m = 0; m < 4; ++m) {
    int row = wr * 64 + m * 16 + (lane & 15);
    aOff[m] = row * BK + (((lane >> 4) ^ ((row >> 1) & 3)) << 3);
  }
  #pragma unroll
  for (int n = 0; n < 4; ++n) {
    int row = wc * 64 + n * 16 + (lane & 15);
    bOff[n] = row * BK + (((lane >> 4) ^ ((row >> 1) & 3)) << 3);
  }

  f32x4 acc[4][4];
  #pragma unroll
  for (int m = 0; m < 4; ++m)
    #pragma unroll
    for (int n = 0; n < 4; ++n)
      acc[m][n] = (f32x4){0.f, 0.f, 0.f, 0.f};

  // prologue: stage tile 0
  #pragma unroll
  for (int i = 0; i < 2; ++i) {
    gload_lds16(Ag + srcOff[i], &As[0][dstOff[i]]);
    gload_lds16(Bg + srcOff[i], &Bs[0][dstOff[i]]);
  }
  __syncthreads();

  int cur = 0;
  for (int t = 0; t < NIT; ++t) {
    if (t + 1 < NIT) {  // stage next tile into other buffer (flight overlaps compute)
      int k0 = (t + 1) * BK;
      #pragma unroll
      for (int i = 0; i < 2; ++i) {
        gload_lds16(Ag + srcOff[i] + k0, &As[cur ^ 1][dstOff[i]]);
        gload_lds16(Bg + srcOff[i] + k0, &Bs[cur ^ 1][dstOff[i]]);
      }
    }
    bf16x8 af[4], bfr[4];
    #pragma unroll
    for (int m = 0; m < 4; ++m) af[m]  = *(const bf16x8*)&As[cur][aOff[m]];
    #pragma unroll
    for (int n = 0; n < 4; ++n) bfr[n] = *(const bf16x8*)&Bs[cur][bOff[n]];
    #pragma unroll
    for (int m = 0; m < 4; ++m)
      #pragma unroll
      for (int n = 0; n < 4; ++n)
        acc[m][n] = __builtin_amdgcn_mfma_f32_16x16x32_bf16(af[m], bfr[n], acc[m][n], 0, 0, 0);
    __syncthreads();   // drains vmcnt (staged) + lgkmcnt (ds_reads)
    cur ^= 1;
  }

  // epilogue: gate uniform per block (BN=128 divides each 512-col gate)
  f16* dst; int gate;
  if (col0 < Hdim)          { dst = zbuf;  gate = 0; }
  else if (col0 < 2 * Hdim) { dst = fbuf;  gate = 1; }
  else                      { dst = ogbuf; gate = 2; }
  const int cb = col0 - gate * Hdim;

  #pragma unroll
  for (int n = 0; n < 4; ++n) {
    int col = cb + wc * 64 + n * 16 + (lane & 15);
    float bv = bias[gate * Hdim + col];
    #pragma unroll
    for (int m = 0; m < 4; ++m) {
      #pragma unroll
      for (int r = 0; r < 4; ++r) {
        int grow = row0 + wr * 64 + m * 16 + (lane >> 4) * 4 + r;
        float y = acc[m][n][r] + bv;
        float v;
        if (gate == 0) {                       // tanh(y) = 1 - 2/(e^{2y}+1)
          float e = __expf(2.f * y);
          v = 1.f - 2.f / (e + 1.f);
        } else {                               // sigmoid
          v = 1.f / (1.f + __expf(-y));
        }
        dst[(size_t)grow * Hdim + col] = (f16)v;
      }
    }
  }
}

// ---------- scan pass A: per-chunk composite (P = prod(1-f), Q = local scan) ----------
// one thread per pair of h-channels
__global__ void __launch_bounds__(256) scanA_kernel(const f16x2* __restrict__ z2,
                                                    const f16x2* __restrict__ f2,
                                                    float* __restrict__ Pb,
                                                    float* __restrict__ Qb) {
  int u  = blockIdx.x * blockDim.x + threadIdx.x;  // 131072 = NCHUNK*B*256
  int hp = u & 255;
  int bc = u >> 8;
  int b  = bc & (Bdim - 1);
  int c  = bc >> 4;
  size_t base = ((size_t)(b * Sdim + c * CLEN)) * 256 + hp;  // in pairs
  float P0 = 1.f, Q0 = 0.f, P1 = 1.f, Q1 = 0.f;
  #pragma unroll 4
  for (int s = 0; s < CLEN; ++s) {
    f16x2 fv = f2[base], zv = z2[base];
    float fa = (float)fv[0], fb = (float)fv[1];
    Q0 += fa * ((float)zv[0] - Q0);  P0 *= (1.f - fa);
    Q1 += fb * ((float)zv[1] - Q1);  P1 *= (1.f - fb);
    base += 256;
  }
  int outi = ((c * Bdim + b) << 9) + hp * 2;
  *(float2*)&Pb[outi] = make_float2(P0, P1);
  *(float2*)&Qb[outi] = make_float2(Q0, Q1);
}

// ---------- scan pass B: scan chunk composites -> h_in per chunk + c_last ----------
__global__ void __launch_bounds__(256) scanB_kernel(const float* __restrict__ Pb,
                                                    const float* __restrict__ Qb,
                                                    float* __restrict__ hin,
                                                    float* __restrict__ c_last) {
  int t = blockIdx.x * blockDim.x + threadIdx.x;  // 8192 = B*H
  int h = t & (Hdim - 1), b = t >> 9;
  float hs = 0.f;
  #pragma unroll
  for (int c = 0; c < NCHUNK; ++c) {
    hin[c * (Bdim * Hdim) + t] = hs;
    int u = ((c * Bdim + b) << 9) + h;
    hs = Pb[u] * hs + Qb[u];
  }
  c_last[t] = hs;
}

// ---------- scan pass C: rerun chunk with correct h_in, fuse out = og * h ----------
__global__ void __launch_bounds__(256) scanC_kernel(const f16x2* __restrict__ z2,
                                                    const f16x2* __restrict__ f2,
                                                    const f16x2* __restrict__ og2,
                                                    const float* __restrict__ hin,
                                                    float2* __restrict__ out2) {
  int u  = blockIdx.x * blockDim.x + threadIdx.x;
  int hp = u & 255;
  int bc = u >> 8;
  int b  = bc & (Bdim - 1);
  int c  = bc >> 4;
  float2 hv = *(const float2*)&hin[c * (Bdim * Hdim) + b * Hdim + hp * 2];
  float h0 = hv.x, h1 = hv.y;
  size_t base = ((size_t)(b * Sdim + c * CLEN)) * 256 + hp;
  #pragma unroll 4
  for (int s = 0; s < CLEN; ++s) {
    f16x2 fv = f2[base], zv = z2[base], ov = og2[base];
    h0 += (float)fv[0] * ((float)zv[0] - h0);
    h1 += (float)fv[1] * ((float)zv[1] - h1);
    out2[base] = make_float2((float)ov[0] * h0, (float)ov[1] * h1);
    base += 256;
  }
}

extern "C" void kernel_launch(void* const* d_in, const int* in_sizes, int n_in,
                              void* d_out, int out_size, void* d_ws, size_t ws_size,
                              hipStream_t stream) {
  const float* inp  = (const float*)d_in[0];
  const float* W    = (const float*)d_in[1];
  const float* bias = (const float*)d_in[2];
  float* out = (float*)d_out;

  char* ws = (char*)d_ws;
  // workspace layout (bytes), total ~273.2 MB
  bf16* Abf = (bf16*)(ws);                   //  67,108,864
  bf16* Wbf = (bf16*)(ws + 67108864);        //   1,572,864
  f16*  zh  = (f16*) (ws + 68681728);        //  67,108,864
  f16*  fh  = (f16*) (ws + 135790592);       //  67,108,864
  f16*  ogh = (f16*) (ws + 202899456);       //  67,108,864
  float* Pb = (float*)(ws + 270008320);      //   1,048,576
  float* Qb = (float*)(ws + 271056896);      //   1,048,576
  float* hin= (float*)(ws + 272105472);      //   1,048,576

  // 1) convert inp and W to bf16
  {
    int n4 = (Mdim * Kdim) / 4;  // 8,388,608
    cvt_kernel<<<n4 / 256, 256, 0, stream>>>((const float4*)inp, (bf16x4*)Abf, n4);
  }
  {
    int n4 = (N3 * Kdim) / 4;    // 196,608
    cvt_kernel<<<n4 / 256, 256, 0, stream>>>((const float4*)W, (bf16x4*)Wbf, n4);
  }
  // 2) GEMM + bias + activations -> fp16 gates
  gemm_act_kernel<<<(Mdim / BM) * (N3 / BN), 256, 0, stream>>>(Abf, Wbf, bias,
                                                               zh, fh, ogh);
  // 3) chunked linear-recurrence scan
  scanA_kernel<<<(NCHUNK * Bdim * 256) / 256, 256, 0, stream>>>(
      (const f16x2*)zh, (const f16x2*)fh, Pb, Qb);
  scanB_kernel<<<(Bdim * Hdim) / 256, 256, 0, stream>>>(Pb, Qb, hin,
                                                        out + (size_t)Mdim * Hdim);
  scanC_kernel<<<(NCHUNK * Bdim * 256) / 256, 256, 0, stream>>>(
      (const f16x2*)zh, (const f16x2*)fh, (const f16x2*)ogh, hin, (float2*)out);
}

// Round 3
// 310.655 us; speedup vs baseline: 1.4486x; 1.0483x over previous
//
#include <hip/hip_runtime.h>
#include <stdint.h>

#define Bdim 16
#define Sdim 4096
#define Hdim 512
#define Mdim (Bdim*Sdim)      // 65536
#define N3   (3*Hdim)         // 1536
#define Kdim 512
#define NCHUNK 64
#define CLEN  (Sdim/NCHUNK)   // 64

typedef __bf16 bf16;
typedef __bf16 bf16x4 __attribute__((ext_vector_type(4)));
typedef __bf16 bf16x8 __attribute__((ext_vector_type(8)));
typedef float  f32x4  __attribute__((ext_vector_type(4)));
typedef _Float16 f16;
typedef _Float16 f16x4 __attribute__((ext_vector_type(4)));
typedef _Float16 f16x8 __attribute__((ext_vector_type(8)));

__device__ inline void gload_lds16(const void* g, void* l) {
  __builtin_amdgcn_global_load_lds(
      (const __attribute__((address_space(1))) uint32_t*)g,
      (__attribute__((address_space(3))) uint32_t*)l, 16, 0, 0);
}

// ---------- fp32 -> bf16 convert (vectorized) ----------
__global__ void __launch_bounds__(256) cvt_kernel(const float4* __restrict__ in,
                                                  bf16x4* __restrict__ out, int n4) {
  int i = blockIdx.x * blockDim.x + threadIdx.x;
  if (i >= n4) return;
  float4 v = in[i];
  bf16x4 o;
  o.x = (bf16)v.x; o.y = (bf16)v.y; o.z = (bf16)v.z; o.w = (bf16)v.w;
  out[i] = o;
}

// ---------- bf16 MFMA GEMM, 256x256 tile, BK=64, 8 waves, fused activations ----------
// A: (M,K) bf16 row-major; Wb: (N,K) bf16 row-major. C = A*Wb^T.
// 2-phase double-buffered LDS (128 KB), (row&7)<<4 XOR swizzle both sides,
// LDS-repacked coalesced f16 epilogue stores.
#define BM 256
#define BN 256
#define BK 64
#define NIT (Kdim/BK)   // 8

__global__ void __launch_bounds__(512, 2) gemm_act_kernel(
    const bf16* __restrict__ A, const bf16* __restrict__ Wb,
    const float* __restrict__ bias,
    f16* __restrict__ zbuf, f16* __restrict__ fbuf, f16* __restrict__ ogbuf) {
  __shared__ char lds[131072];  // buf t: A at t*65536, B at t*65536+32768
  const int tid  = threadIdx.x;
  const int wid  = tid >> 6;
  const int lane = tid & 63;
  const int wr = wid >> 2, wc = wid & 3;   // 2(M) x 4(N) wave grid; wave tile 128x64
  // XCD-chunked bijective swizzle: 1536 blocks = 8 XCDs x 192
  const int bid = blockIdx.x;
  const int wg  = (bid & 7) * 192 + (bid >> 3);
  const int mt = wg / (N3 / BN);           // 256 M-tiles
  const int nt = wg % (N3 / BN);           // 6 N-tiles (inner -> A reuse per XCD)
  const int row0 = mt * BM, col0 = nt * BN;

  const bf16* Ag = A  + (size_t)row0 * Kdim;
  const bf16* Bg = Wb + (size_t)col0 * Kdim;

  // staging: K-tile operand = 256 rows x 64 k = 32KB = 2048 x 16B chunks.
  // chunk c: row r=c>>3, slot=c&7 (8x16B per row). LDS dest linear,
  // source pre-swizzled: slot_s = slot ^ (r&7)  (XOR of byte bits 4..6 w/ row bits 0..2)
  uint32_t srcOff[4], dstB[4];
  #pragma unroll
  for (int i = 0; i < 4; ++i) {
    int c = i * 512 + tid;
    int r = c >> 3, slot = c & 7;
    srcOff[i] = (uint32_t)(r * Kdim + ((slot ^ (r & 7)) << 3));  // elements
    dstB[i]   = (uint32_t)((i * 512 + wid * 64) * 16);           // bytes, wave-uniform
  }
  // fragment byte offsets within a 32KB operand buffer (kk=0; kk=1 is ^64)
  uint32_t aOff[8], bOff[4];
  #pragma unroll
  for (int m = 0; m < 8; ++m) {
    int row = wr * 128 + m * 16 + (lane & 15);
    aOff[m] = (uint32_t)((row * 128 + (lane >> 4) * 16) ^ ((row & 7) << 4));
  }
  #pragma unroll
  for (int n = 0; n < 4; ++n) {
    int row = wc * 64 + n * 16 + (lane & 15);
    bOff[n] = (uint32_t)((row * 128 + (lane >> 4) * 16) ^ ((row & 7) << 4));
  }

  f32x4 acc[8][4];
  #pragma unroll
  for (int m = 0; m < 8; ++m)
    #pragma unroll
    for (int n = 0; n < 4; ++n)
      acc[m][n] = (f32x4){0.f, 0.f, 0.f, 0.f};

  // prologue: stage K-tile 0
  {
    char* Ad = lds; char* Bd = lds + 32768;
    #pragma unroll
    for (int i = 0; i < 4; ++i) gload_lds16(Ag + srcOff[i], Ad + dstB[i]);
    #pragma unroll
    for (int i = 0; i < 4; ++i) gload_lds16(Bg + srcOff[i], Bd + dstB[i]);
  }
  __syncthreads();

  for (int t = 0; t < NIT; ++t) {
    if (t + 1 < NIT) {  // stage next K-tile into other buffer (issue-early)
      int k0 = (t + 1) * BK;
      char* Ad = lds + ((t + 1) & 1) * 65536; char* Bd = Ad + 32768;
      #pragma unroll
      for (int i = 0; i < 4; ++i) gload_lds16(Ag + srcOff[i] + k0, Ad + dstB[i]);
      #pragma unroll
      for (int i = 0; i < 4; ++i) gload_lds16(Bg + srcOff[i] + k0, Bd + dstB[i]);
    }
    const char* Ab = lds + (t & 1) * 65536;
    const char* Bb = Ab + 32768;
    #pragma unroll
    for (int kk = 0; kk < 2; ++kk) {
      bf16x8 af[8], bf[4];
      #pragma unroll
      for (int m = 0; m < 8; ++m) af[m] = *(const bf16x8*)(Ab + (aOff[m] ^ (kk << 6)));
      #pragma unroll
      for (int n = 0; n < 4; ++n) bf[n] = *(const bf16x8*)(Bb + (bOff[n] ^ (kk << 6)));
      #pragma unroll
      for (int m = 0; m < 8; ++m)
        #pragma unroll
        for (int n = 0; n < 4; ++n)
          acc[m][n] = __builtin_amdgcn_mfma_f32_16x16x32_bf16(af[m], bf[n], acc[m][n], 0, 0, 0);
    }
    __syncthreads();  // drains vmcnt (next-tile stage) + lgkmcnt; MFMA shadowed the flight
  }

  // ---- epilogue: activation, repack via LDS, coalesced f16x8 stores ----
  const int gate = nt >> 1;                 // BN=256 divides each 512-col gate
  const int cb   = (nt & 1) * 256;
  f16* dst = (gate == 0) ? zbuf : ((gate == 1) ? fbuf : ogbuf);
  float bv[4];
  #pragma unroll
  for (int n = 0; n < 4; ++n)
    bv[n] = bias[gate * Hdim + cb + wc * 64 + n * 16 + (lane & 15)];

  // write phase: scatter f16 into swizzled 256x256 tile (row stride 512B)
  #pragma unroll
  for (int m = 0; m < 8; ++m) {
    #pragma unroll
    for (int n = 0; n < 4; ++n) {
      int col = wc * 64 + n * 16 + (lane & 15);
      #pragma unroll
      for (int r = 0; r < 4; ++r) {
        int row = wr * 128 + m * 16 + (lane >> 4) * 4 + r;
        float y = acc[m][n][r] + bv[n];
        float v;
        if (gate == 0) {                       // tanh(y) = 1 - 2/(e^{2y}+1)
          float e = __expf(2.f * y);
          v = 1.f - 2.f / (e + 1.f);
        } else {                               // sigmoid
          v = 1.f / (1.f + __expf(-y));
        }
        uint32_t byte = (uint32_t)(row * 512 + col * 2) ^ ((uint32_t)(row & 7) << 4);
        *(f16*)(lds + byte) = (f16)v;
      }
    }
  }
  __syncthreads();
  // read phase: 16 rounds x 512 threads x 16B, contiguous global stores
  #pragma unroll
  for (int j = 0; j < 16; ++j) {
    int c = j * 512 + tid;
    int row = c >> 5, col8 = c & 31;        // 32 x 16B chunks per 512B row
    uint32_t byte = (uint32_t)(row * 512 + col8 * 16) ^ ((uint32_t)(row & 7) << 4);
    f16x8 v = *(const f16x8*)(lds + byte);
    *(f16x8*)&dst[(size_t)(row0 + row) * Hdim + cb + col8 * 8] = v;
  }
}

// ---------- scan pass A: per-chunk composite (P = prod(1-f), Q = local scan) ----------
// one thread per 4 h-channels (8B f16x4 loads)
__global__ void __launch_bounds__(256) scanA_kernel(const f16x4* __restrict__ z4,
                                                    const f16x4* __restrict__ f4,
                                                    float* __restrict__ Pb,
                                                    float* __restrict__ Qb) {
  int u  = blockIdx.x * blockDim.x + threadIdx.x;  // 131072 = NCHUNK*B*128
  int hq = u & 127;
  int bc = u >> 7;
  int b  = bc & (Bdim - 1);
  int c  = bc >> 4;
  size_t base = ((size_t)(b * Sdim + c * CLEN)) * 128 + hq;  // in quads
  float P[4] = {1.f, 1.f, 1.f, 1.f}, Q[4] = {0.f, 0.f, 0.f, 0.f};
  #pragma unroll 4
  for (int s = 0; s < CLEN; ++s) {
    f16x4 fv = f4[base], zv = z4[base];
    #pragma unroll
    for (int j = 0; j < 4; ++j) {
      float f = (float)fv[j];
      Q[j] += f * ((float)zv[j] - Q[j]);
      P[j] *= (1.f - f);
    }
    base += 128;
  }
  int outi = ((c * Bdim + b) << 9) + hq * 4;
  *(float4*)&Pb[outi] = make_float4(P[0], P[1], P[2], P[3]);
  *(float4*)&Qb[outi] = make_float4(Q[0], Q[1], Q[2], Q[3]);
}

// ---------- scan pass B: scan chunk composites -> h_in per chunk + c_last ----------
__global__ void __launch_bounds__(256) scanB_kernel(const float* __restrict__ Pb,
                                                    const float* __restrict__ Qb,
                                                    float* __restrict__ hin,
                                                    float* __restrict__ c_last) {
  int t = blockIdx.x * blockDim.x + threadIdx.x;  // 8192 = B*H
  int h = t & (Hdim - 1), b = t >> 9;
  float hs = 0.f;
  #pragma unroll 8
  for (int c = 0; c < NCHUNK; ++c) {
    hin[c * (Bdim * Hdim) + t] = hs;
    int u = ((c * Bdim + b) << 9) + h;
    hs = Pb[u] * hs + Qb[u];
  }
  c_last[t] = hs;
}

// ---------- scan pass C: rerun chunk with correct h_in, fuse out = og * h ----------
__global__ void __launch_bounds__(256) scanC_kernel(const f16x4* __restrict__ z4,
                                                    const f16x4* __restrict__ f4,
                                                    const f16x4* __restrict__ og4,
                                                    const float* __restrict__ hin,
                                                    float4* __restrict__ out4) {
  int u  = blockIdx.x * blockDim.x + threadIdx.x;
  int hq = u & 127;
  int bc = u >> 7;
  int b  = bc & (Bdim - 1);
  int c  = bc >> 4;
  float4 hv = *(const float4*)&hin[c * (Bdim * Hdim) + b * Hdim + hq * 4];
  float h[4] = {hv.x, hv.y, hv.z, hv.w};
  size_t base = ((size_t)(b * Sdim + c * CLEN)) * 128 + hq;
  #pragma unroll 4
  for (int s = 0; s < CLEN; ++s) {
    f16x4 fv = f4[base], zv = z4[base], ov = og4[base];
    float4 o;
    #pragma unroll
    for (int j = 0; j < 4; ++j) {
      h[j] += (float)fv[j] * ((float)zv[j] - h[j]);
    }
    o.x = (float)ov[0] * h[0]; o.y = (float)ov[1] * h[1];
    o.z = (float)ov[2] * h[2]; o.w = (float)ov[3] * h[3];
    out4[base] = o;
    base += 128;
  }
}

extern "C" void kernel_launch(void* const* d_in, const int* in_sizes, int n_in,
                              void* d_out, int out_size, void* d_ws, size_t ws_size,
                              hipStream_t stream) {
  const float* inp  = (const float*)d_in[0];
  const float* W    = (const float*)d_in[1];
  const float* bias = (const float*)d_in[2];
  float* out = (float*)d_out;

  char* ws = (char*)d_ws;
  // workspace layout (bytes), total ~276 MB
  bf16* Abf = (bf16*)(ws);                   //  67,108,864
  bf16* Wbf = (bf16*)(ws + 67108864);        //   1,572,864
  f16*  zh  = (f16*) (ws + 68681728);        //  67,108,864
  f16*  fh  = (f16*) (ws + 135790592);       //  67,108,864
  f16*  ogh = (f16*) (ws + 202899456);       //  67,108,864
  float* Pb = (float*)(ws + 270008320);      //   2,097,152
  float* Qb = (float*)(ws + 272105472);      //   2,097,152
  float* hin= (float*)(ws + 274202624);      //   2,097,152

  // 1) convert inp and W to bf16
  {
    int n4 = (Mdim * Kdim) / 4;  // 8,388,608
    cvt_kernel<<<n4 / 256, 256, 0, stream>>>((const float4*)inp, (bf16x4*)Abf, n4);
  }
  {
    int n4 = (N3 * Kdim) / 4;    // 196,608
    cvt_kernel<<<n4 / 256, 256, 0, stream>>>((const float4*)W, (bf16x4*)Wbf, n4);
  }
  // 2) GEMM + bias + activations -> fp16 gates
  gemm_act_kernel<<<(Mdim / BM) * (N3 / BN), 512, 0, stream>>>(Abf, Wbf, bias,
                                                               zh, fh, ogh);
  // 3) chunked linear-recurrence scan
  scanA_kernel<<<(NCHUNK * Bdim * 128) / 256, 256, 0, stream>>>(
      (const f16x4*)zh, (const f16x4*)fh, Pb, Qb);
  scanB_kernel<<<(Bdim * Hdim) / 256, 256, 0, stream>>>(Pb, Qb, hin,
                                                        out + (size_t)Mdim * Hdim);
  scanC_kernel<<<(NCHUNK * Bdim * 128) / 256, 256, 0, stream>>>(
      (const f16x4*)zh, (const f16x4*)fh, (const f16x4*)ogh, hin, (float4*)out);
}